// Round 1
// baseline (3014.319 us; speedup 1.0000x reference)
//
#include <hip/hip_runtime.h>
#include <hip/hip_bf16.h>
#include <math.h>

#define Bb   128
#define Ss   512
#define Ff   64
#define Hh   512
#define NGc  2053          // 4*H + 5
#define Kk   576           // F + H

// workspace layout (bytes)
#define OFF_FLAGS 0                        // 8 groups x 32 wblocks x 4 waves x 4B = 4 KB (zeroed)
#define OFF_HB    4096                     // 2 parities x 8 groups x 32768 B tagged h tiles
#define OFF_HFIN  528384                   // B*H fp32
#define OFF_CFIN  790528                   // 5 x B*H fp32
#define OFF_R1    2101248                  // 128x256 fp32
#define OFF_R2    2232320                  // 128x128 fp32
#define OFF_Y1    2297856                  // 5 x 128x256 fp32

typedef __attribute__((ext_vector_type(8))) short short8;
typedef __attribute__((ext_vector_type(4))) float f32x4;
typedef __attribute__((ext_vector_type(4))) int   i32x4a;

__device__ __forceinline__ unsigned short f2bf(float f) {
    union { float f; unsigned u; } v; v.f = f;
    unsigned r = v.u + 0x7fffu + ((v.u >> 16) & 1u);
    return (unsigned short)(r >> 16);
}

__device__ __forceinline__ float frcp(float x) { return __builtin_amdgcn_rcpf(x); }

// overflow-safe fast tanh via v_exp + v_rcp (no slow fp32 div sequence)
__device__ __forceinline__ float ftanh(float x) {
    float ax = fabsf(x);
    float t  = __expf(-2.f * ax);
    float r  = (1.f - t) * frcp(1.f + t);
    return copysignf(r, x);
}
__device__ __forceinline__ float fsig(float x) {
    return frcp(1.f + __expf(-x));
}

// 8 coalescing LLC-direct 16B loads covering this wave's 4 tagged h k-blocks.
// Two base regs: %8 = hb, %9 = hb + 4096 (13-bit signed imm caps at 4095).
#define HL8(T, a, a2)                                                  \
  asm volatile(                                                        \
    "global_load_dwordx4 %0, %8, off sc0 sc1\n\t"                      \
    "global_load_dwordx4 %1, %8, off offset:16 sc0 sc1\n\t"            \
    "global_load_dwordx4 %2, %8, off offset:2048 sc0 sc1\n\t"          \
    "global_load_dwordx4 %3, %8, off offset:2064 sc0 sc1\n\t"          \
    "global_load_dwordx4 %4, %9, off sc0 sc1\n\t"                      \
    "global_load_dwordx4 %5, %9, off offset:16 sc0 sc1\n\t"            \
    "global_load_dwordx4 %6, %9, off offset:2048 sc0 sc1\n\t"          \
    "global_load_dwordx4 %7, %9, off offset:2064 sc0 sc1\n\t"          \
    "s_waitcnt vmcnt(0)"                                               \
    : "=v"(T[0]), "=v"(T[1]), "=v"(T[2]), "=v"(T[3]),                  \
      "=v"(T[4]), "=v"(T[5]), "=v"(T[6]), "=v"(T[7])                   \
    : "v"(a), "v"(a2) : "memory")

__global__ __launch_bounds__(256, 1) void mclstm_main(
    const float* __restrict__ xin, const float* __restrict__ Wm,
    const float* __restrict__ Um,  const float* __restrict__ k1,
    const float* __restrict__ bias, const float* __restrict__ bias1,
    float* __restrict__ out, unsigned char* __restrict__ ws)
{
    // gate partials: [parity][wave][row][unit][{i,f,g,o}] -> 16B vector exchange
    __shared__ __align__(16) float predG[2][4][16][16][4];   // 32 KB
    // d partials:   [parity][c][row][wave] -> consumer reads one b128 per c
    __shared__ __align__(16) float predD[2][5][16][4];       // 2.5 KB

    const int tid   = threadIdx.x;
    const int bid   = blockIdx.x;
    const int g_id  = bid & 7;        // batch-row group
    const int w_id  = bid >> 3;       // hidden-unit block [0,32)
    const int lane  = tid & 63;
    const int wv    = tid >> 6;
    const int j0    = w_id * 16;
    const int col16 = lane & 15;
    const int quad  = lane >> 4;

    float* hfin = (float*)(ws + OFF_HFIN);
    float* cfin = (float*)(ws + OFF_CFIN);

    // ---- B-fragments in REGISTERS (constant across all steps) ----
    short8 Bf[5][5];
#pragma unroll
    for (int i = 0; i < 4; ++i) {
        int kb = (wv * 4 + i) * 32 + quad * 8;     // row in U
#pragma unroll
        for (int nt = 0; nt < 5; ++nt) {
            int col = (nt < 4) ? (nt * Hh + j0 + col16)
                               : ((col16 < 5) ? (4 * Hh + col16) : -1);
            short8 b;
#pragma unroll
            for (int j = 0; j < 8; ++j) {
                float v = (col >= 0) ? Um[(size_t)(kb + j) * NGc + col] : 0.f;
                b[j] = (short)f2bf(v);
            }
            Bf[1 + i][nt] = b;
        }
    }
    if (wv < 2) {
        int kb = wv * 32 + quad * 8;               // row in W
#pragma unroll
        for (int nt = 0; nt < 5; ++nt) {
            int col = (nt < 4) ? (nt * Hh + j0 + col16)
                               : ((col16 < 5) ? (4 * Hh + col16) : -1);
            short8 b;
#pragma unroll
            for (int j = 0; j < 8; ++j) {
                float v = (col >= 0) ? Wm[(size_t)(kb + j) * NGc + col] : 0.f;
                b[j] = (short)f2bf(v);
            }
            Bf[0][nt] = b;
        }
    }

    // ---- per-thread cell constants: thread owns (row=tid>>4, unit=tid&15) ----
    const int rrow = tid >> 4, uu = tid & 15;
    const int u_g  = j0 + uu;
    const float bi = bias[0 * Hh + u_g], bf = bias[1 * Hh + u_g];
    const float bg = bias[2 * Hh + u_g], bo = bias[3 * Hh + u_g];
    float bd[5], kv[5];
#pragma unroll
    for (int c = 0; c < 5; ++c) { bd[c] = bias[4 * Hh + c]; kv[c] = k1[c * Hh + u_g]; }
    const float s1v = bias1[u_g], s2v = bias1[Hh + u_g];
    float cpreg = 0.f;

    // publish offset: unit u_g is k-index; tile layout [kb 2048B][quad 512B][row 32B][jj 4B]
    const int kb_p = u_g >> 5, kin = u_g & 31;
    const unsigned pub_off = (unsigned)(kb_p * 2048 + (kin >> 3) * 512 + rrow * 32 + (kin & 7) * 4);

    // ---- readiness-flag addresses (t-invariant) ----
    // producer sub-flag (g_id, w_id, wv): one dword, monotone step counter.
    unsigned* const flag_pub = (unsigned*)(ws + OFF_FLAGS) + (g_id * 128 + w_id * 4 + wv);
    // consumer wave wv needs producers w in [8*wv, 8*wv+8), all 4 of their waves
    // = flag indices [32*wv, 32*wv+32). lane L polls flag 32*wv + (L&31).
    const unsigned long long flag_poll_addr = (unsigned long long)
        ((unsigned*)(ws + OFF_FLAGS) + (g_id * 128 + wv * 32 + (lane & 31)));

    __syncthreads();

    for (int t = 0; t < Ss; ++t) {
        char* hcur = (char*)ws + OFF_HB + (((t & 1) * 8 + g_id) * 32768);
        char* hnxt = (char*)ws + OFF_HB + ((((t + 1) & 1) * 8 + g_id) * 32768);
        const int pp = t & 1;

        f32x4 acc[5];
#pragma unroll
        for (int nt = 0; nt < 5; ++nt) { f32x4 z = {0.f, 0.f, 0.f, 0.f}; acc[nt] = z; }

        // ---- waves 0,1: own one x k-block; load + MFMA BEFORE poll ----
        if (wv < 2) {
            short8 Ax;
            const float* p = xin + ((size_t)(16 * g_id + col16) * Ss + t) * Ff
                           + wv * 32 + quad * 8;
            f32x4 f0 = *(const f32x4*)(p);
            f32x4 f1 = *(const f32x4*)(p + 4);
#pragma unroll
            for (int j = 0; j < 4; ++j) {
                Ax[j]     = (short)f2bf(f0[j]);
                Ax[4 + j] = (short)f2bf(f1[j]);
            }
#pragma unroll
            for (int nt = 0; nt < 5; ++nt)
                acc[nt] = __builtin_amdgcn_mfma_f32_16x16x32_bf16(Ax, Bf[0][nt], acc[nt], 0, 0, 0);
        }

        // ---- cheap readiness poll: 4B/lane flag reads (hint only; tags below
        // ---- stay authoritative). Cuts LLC poll traffic ~150x vs re-reading
        // ---- the 8KB payload per iteration. ----
        {
            for (int it = 0; it < (1 << 22); ++it) {
                unsigned f;
                asm volatile(
                    "global_load_dword %0, %1, off sc0 sc1\n\t"
                    "s_waitcnt vmcnt(0)"
                    : "=v"(f) : "v"(flag_poll_addr) : "memory");
                if (__all((int)(f >= (unsigned)t))) break;
            }
        }

        // ---- tagged payload load + verify (expect ~1 iteration now) ----
        i32x4a T[8];
        {
            unsigned long long hb = (unsigned long long)
                (hcur + (wv * 4) * 2048 + quad * 512 + col16 * 32);
            unsigned long long hb2 = hb + 4096;
            const unsigned expect = (unsigned)t << 16;
            for (int it = 0; it < (1 << 22); ++it) {
                HL8(T, hb, hb2);
                unsigned diff = 0u;
#pragma unroll
                for (int i = 0; i < 8; ++i)
#pragma unroll
                    for (int j = 0; j < 4; ++j)
                        diff |= ((unsigned)T[i][j]) ^ expect;
                if (__all((int)((diff >> 16) == 0u))) break;
            }
        }

        // ---- repack tagged dwords -> bf16 A-frags, MFMA ----
#pragma unroll
        for (int i = 0; i < 4; ++i) {
            short8 a;
#pragma unroll
            for (int j = 0; j < 4; ++j) {
                a[j]     = (short)(T[2 * i][j] & 0xFFFF);
                a[4 + j] = (short)(T[2 * i + 1][j] & 0xFFFF);
            }
#pragma unroll
            for (int nt = 0; nt < 5; ++nt)
                acc[nt] = __builtin_amdgcn_mfma_f32_16x16x32_bf16(a, Bf[1 + i][nt], acc[nt], 0, 0, 0);
        }

        // ---- write K-split partials: gates as one f32x4 per (row,unit) ----
#pragma unroll
        for (int j = 0; j < 4; ++j) {
            f32x4 g4 = {acc[0][j], acc[1][j], acc[2][j], acc[3][j]};
            *(f32x4*)&predG[pp][wv][quad * 4 + j][col16][0] = g4;
        }
        if (col16 < 5) {
#pragma unroll
            for (int j = 0; j < 4; ++j)
                predD[pp][col16][quad * 4 + j][wv] = acc[4][j];
        }
        __syncthreads();                  // the ONLY barrier per step

        // ---- reduce + cell update + tagged register->LLC publish ----
        {
            f32x4 g4 = {bi, bf, bg, bo};
#pragma unroll
            for (int w = 0; w < 4; ++w) {
                f32x4 p = *(const f32x4*)&predG[pp][w][rrow][uu][0];
                g4 += p;
            }
            float dv[5];
#pragma unroll
            for (int c = 0; c < 5; ++c) {
                f32x4 dp = *(const f32x4*)&predD[pp][c][rrow][0];
                dv[c] = bd[c] + ((dp[0] + dp[1]) + (dp[2] + dp[3]));
            }
            // softmax(tanh(.)): tanh in [-1,1] -> no max-subtraction needed
            float sden = 0.f;
#pragma unroll
            for (int c = 0; c < 5; ++c) { dv[c] = __expf(ftanh(dv[c])); sden += dv[c]; }
            float inv = frcp(sden);
#pragma unroll
            for (int c = 0; c < 5; ++c) dv[c] *= inv;

            float i_ = fsig(g4[0]);
            float f_ = fsig(g4[1]);
            float g_ = ftanh(g4[2]);
            float o_ = fsig(g4[3]);
            float c1v = ftanh(g_);
            float c5v = cpreg;
            float c3v = f_ * c5v + i_ * g_;
            float c2v = s2v * c3v + (1.f - s2v) * c1v;
            float c4v = s1v * c3v + (1.f - s1v) * c5v;
            float cn = dv[0] * kv[0] * c1v + dv[1] * kv[1] * c2v + dv[2] * kv[2] * c3v
                     + dv[3] * kv[3] * c4v + dv[4] * kv[4] * c5v;
            float hn = o_ * ftanh(cn);
            cpreg = cn;

            if (t < Ss - 1) {
                unsigned word = ((unsigned)(t + 1) << 16) | (unsigned)f2bf(hn);
                __hip_atomic_store((unsigned*)(hnxt + pub_off), word,
                                   __ATOMIC_RELAXED, __HIP_MEMORY_SCOPE_AGENT);
                // readiness hint: issued right after the payload store in
                // program order. No fence needed: if the flag races ahead of
                // a payload word, the consumer's tag-verify loop spins it out.
                if (lane == 0)
                    __hip_atomic_store(flag_pub, (unsigned)(t + 1),
                                       __ATOMIC_RELAXED, __HIP_MEMORY_SCOPE_AGENT);
            } else {
                size_t off = (size_t)(16 * g_id + rrow) * Hh + u_g;
                hfin[off] = hn;
                cfin[0 * Bb * Hh + off] = c1v;
                cfin[1 * Bb * Hh + off] = c2v;
                cfin[2 * Bb * Hh + off] = c3v;
                cfin[3 * Bb * Hh + off] = c4v;
                cfin[4 * Bb * Hh + off] = c5v;
                if (w_id == 0 && uu == 0) {
#pragma unroll
                    for (int c = 0; c < 5; ++c)
                        out[1408 + (16 * g_id + rrow) * 5 + c] = dv[c];
                }
            }
        }
        // no end-of-step barrier: pred is parity-buffered; the next step's
        // shared barrier orders read(t) before write(t+2).
    }
}

// ---- heads: stage A: r1 = relu(h@rw1+rb1); y1[hd] = relu(c_hd@dw1+db1) ----
__global__ __launch_bounds__(256) void stageA(const unsigned char* __restrict__ ws,
    const float* __restrict__ rw1, const float* __restrict__ rb1,
    const float* __restrict__ dw1, const float* __restrict__ db1)
{
    __shared__ float sW[512 * 17];
    const int tid = threadIdx.x;
    const int blk = blockIdx.x;
    const float* hfin = (const float*)(ws + OFF_HFIN);
    const float* cfin = (const float*)(ws + OFF_CFIN);
    float* r1 = (float*)(ws + OFF_R1);
    float* y1 = (float*)(ws + OFF_Y1);

    const float* src; const float* Wm; const float* bv; float* dst; int cblk;
    if (blk < 16) { src = hfin; Wm = rw1; bv = rb1; dst = r1; cblk = blk; }
    else {
        int hd = (blk - 16) >> 4; cblk = (blk - 16) & 15;
        src = cfin + (size_t)hd * Bb * Hh; Wm = dw1; bv = db1;
        dst = y1 + (size_t)hd * Bb * 256;
    }
    for (int e = tid; e < 512 * 16; e += 256) {
        int k = e >> 4, c = e & 15;
        sW[k * 17 + c] = Wm[(size_t)k * 256 + cblk * 16 + c];
    }
    __syncthreads();
    for (int e = tid; e < 128 * 16; e += 256) {
        int r = e >> 4, c = e & 15;
        float a = bv[cblk * 16 + c];
        const float* sp = src + (size_t)r * 512;
        for (int k = 0; k < 512; k += 4) {
            f32x4 h4 = *(const f32x4*)(sp + k);
            a += h4[0] * sW[(k + 0) * 17 + c] + h4[1] * sW[(k + 1) * 17 + c]
               + h4[2] * sW[(k + 2) * 17 + c] + h4[3] * sW[(k + 3) * 17 + c];
        }
        dst[(size_t)r * 256 + cblk * 16 + c] = fmaxf(a, 0.f);
    }
}

// ---- stage B: r2 = relu(r1@rw2+rb2) ----
__global__ __launch_bounds__(256) void stageB(const unsigned char* __restrict__ ws,
    const float* __restrict__ rw2, const float* __restrict__ rb2)
{
    __shared__ float sW[256 * 17];
    const int tid = threadIdx.x;
    const int cblk = blockIdx.x;
    const float* r1 = (const float*)(ws + OFF_R1);
    float* r2 = (float*)(ws + OFF_R2);
    for (int e = tid; e < 256 * 16; e += 256) {
        int k = e >> 4, c = e & 15;
        sW[k * 17 + c] = rw2[(size_t)k * 128 + cblk * 16 + c];
    }
    __syncthreads();
    for (int e = tid; e < 128 * 16; e += 256) {
        int r = e >> 4, c = e & 15;
        float a = rb2[cblk * 16 + c];
        const float* sp = r1 + (size_t)r * 256;
        for (int k = 0; k < 256; k += 4) {
            f32x4 h4 = *(const f32x4*)(sp + k);
            a += h4[0] * sW[(k + 0) * 17 + c] + h4[1] * sW[(k + 1) * 17 + c]
               + h4[2] * sW[(k + 2) * 17 + c] + h4[3] * sW[(k + 3) * 17 + c];
        }
        r2[(size_t)r * 128 + cblk * 16 + c] = fmaxf(a, 0.f);
    }
}

// ---- stage C: BN + final projections + log_softmax ----
__global__ __launch_bounds__(256) void stageC(const unsigned char* __restrict__ ws,
    const float* __restrict__ rbng, const float* __restrict__ rbnb,
    const float* __restrict__ rw3,  const float* __restrict__ rb3,
    const float* __restrict__ dbng, const float* __restrict__ dbnb,
    const float* __restrict__ dw2,  const float* __restrict__ db2,
    float* __restrict__ out)
{
    __shared__ float sc[256], sh[256];
    const int tid = threadIdx.x;
    const int blk = blockIdx.x;
    const float* r2 = (const float*)(ws + OFF_R2);
    const float* y1 = (const float*)(ws + OFF_Y1);
    if (blk == 0) {
        if (tid < 128) {
            int c = tid; float s = 0.f, s2 = 0.f;
            for (int r = 0; r < 128; ++r) { float x = r2[r * 128 + c]; s += x; s2 += x * x; }
            float m = s * (1.f / 128.f), v = s2 * (1.f / 128.f) - m * m;
            float sca = rbng[c] * rsqrtf(v + 1e-5f);
            sc[c] = sca; sh[c] = rbnb[c] - m * sca;
        }
        __syncthreads();
        if (tid < 128) {
            int r = tid; float a = rb3[0];
            for (int c = 0; c < 128; ++c)
                a += (r2[r * 128 + c] * sc[c] + sh[c]) * rw3[c];
            out[r] = a;
        }
    } else {
        int hd = blk - 1;
        const float* y = y1 + (size_t)hd * 128 * 256;
        {
            int c = tid; float s = 0.f, s2 = 0.f;
            for (int r = 0; r < 128; ++r) { float x = y[r * 256 + c]; s += x; s2 += x * x; }
            float m = s * (1.f / 128.f), v = s2 * (1.f / 128.f) - m * m;
            float sca = dbng[c] * rsqrtf(v + 1e-5f);
            sc[c] = sca; sh[c] = dbnb[c] - m * sca;
        }
        __syncthreads();
        if (tid < 128) {
            int r = tid;
            float z0 = db2[0], z1 = db2[1];
            for (int c = 0; c < 256; ++c) {
                float yn = y[r * 256 + c] * sc[c] + sh[c];
                z0 += yn * dw2[c * 2 + 0];
                z1 += yn * dw2[c * 2 + 1];
            }
            float mx = fmaxf(z0, z1);
            float ls = mx + logf(__expf(z0 - mx) + __expf(z1 - mx));
            out[128 + hd * 256 + r * 2 + 0] = z0 - ls;
            out[128 + hd * 256 + r * 2 + 1] = z1 - ls;
        }
    }
}

extern "C" void kernel_launch(void* const* d_in, const int* in_sizes, int n_in,
                              void* d_out, int out_size, void* d_ws, size_t ws_size,
                              hipStream_t stream) {
    const float* x    = (const float*)d_in[0];
    const float* Wm   = (const float*)d_in[1];
    const float* Um   = (const float*)d_in[2];
    const float* k1   = (const float*)d_in[3];
    const float* bias = (const float*)d_in[4];
    const float* b1   = (const float*)d_in[5];
    const float* rw1  = (const float*)d_in[6];
    const float* rb1  = (const float*)d_in[7];
    const float* rw2  = (const float*)d_in[8];
    const float* rb2  = (const float*)d_in[9];
    const float* rbng = (const float*)d_in[10];
    const float* rbnb = (const float*)d_in[11];
    const float* rw3  = (const float*)d_in[12];
    const float* rb3  = (const float*)d_in[13];
    const float* dw1  = (const float*)d_in[14];
    const float* db1  = (const float*)d_in[15];
    const float* dbng = (const float*)d_in[16];
    const float* dbnb = (const float*)d_in[17];
    const float* dw2  = (const float*)d_in[18];
    const float* db2  = (const float*)d_in[19];
    (void)in_sizes; (void)n_in; (void)out_size; (void)ws_size;

    // zero flags (offset 0) + both tagged h tile parities (tag 0 == step 0, h0 = 0)
    hipMemsetAsync(d_ws, 0, OFF_HFIN, stream);

    mclstm_main<<<256, 256, 0, stream>>>(x, Wm, Um, k1, bias, b1,
                                         (float*)d_out, (unsigned char*)d_ws);
    stageA<<<96, 256, 0, stream>>>((const unsigned char*)d_ws, rw1, rb1, dw1, db1);
    stageB<<<8, 256, 0, stream>>>((const unsigned char*)d_ws, rw2, rb2);
    stageC<<<6, 256, 0, stream>>>((const unsigned char*)d_ws, rbng, rbnb, rw3, rb3,
                                  dbng, dbnb, dw2, db2, (float*)d_out);
}

// Round 2
// 1446.632 us; speedup vs baseline: 2.0837x; 2.0837x over previous
//
#include <hip/hip_runtime.h>
#include <hip/hip_bf16.h>
#include <math.h>

#define Bb   128
#define Ss   512
#define Ff   64
#define Hh   512
#define NGc  2053          // 4*H + 5
#define Kk   576           // F + H

// workspace layout (bytes)
#define OFF_HB    4096                     // 2 parities x 8 groups x 32768 B tagged h tiles
#define OFF_HFIN  528384                   // B*H fp32
#define OFF_CFIN  790528                   // 5 x B*H fp32
#define OFF_R1    2101248                  // 128x256 fp32
#define OFF_R2    2232320                  // 128x128 fp32
#define OFF_Y1    2297856                  // 5 x 128x256 fp32

typedef __attribute__((ext_vector_type(8))) short short8;
typedef __attribute__((ext_vector_type(4))) float f32x4;
typedef __attribute__((ext_vector_type(4))) int   i32x4a;

__device__ __forceinline__ unsigned short f2bf(float f) {
    union { float f; unsigned u; } v; v.f = f;
    unsigned r = v.u + 0x7fffu + ((v.u >> 16) & 1u);
    return (unsigned short)(r >> 16);
}

__device__ __forceinline__ float frcp(float x) { return __builtin_amdgcn_rcpf(x); }

// overflow-safe fast tanh via v_exp + v_rcp (no slow fp32 div sequence)
__device__ __forceinline__ float ftanh(float x) {
    float ax = fabsf(x);
    float t  = __expf(-2.f * ax);
    float r  = (1.f - t) * frcp(1.f + t);
    return copysignf(r, x);
}
__device__ __forceinline__ float fsig(float x) {
    return frcp(1.f + __expf(-x));
}

// 8 coalescing LLC-direct 16B loads covering this wave's 4 tagged h k-blocks.
// Two base regs: %8 = hb, %9 = hb + 4096 (13-bit signed imm caps at 4095).
#define HL8(T, a, a2)                                                  \
  asm volatile(                                                        \
    "global_load_dwordx4 %0, %8, off sc0 sc1\n\t"                      \
    "global_load_dwordx4 %1, %8, off offset:16 sc0 sc1\n\t"            \
    "global_load_dwordx4 %2, %8, off offset:2048 sc0 sc1\n\t"          \
    "global_load_dwordx4 %3, %8, off offset:2064 sc0 sc1\n\t"          \
    "global_load_dwordx4 %4, %9, off sc0 sc1\n\t"                      \
    "global_load_dwordx4 %5, %9, off offset:16 sc0 sc1\n\t"            \
    "global_load_dwordx4 %6, %9, off offset:2048 sc0 sc1\n\t"          \
    "global_load_dwordx4 %7, %9, off offset:2064 sc0 sc1\n\t"          \
    "s_waitcnt vmcnt(0)"                                               \
    : "=v"(T[0]), "=v"(T[1]), "=v"(T[2]), "=v"(T[3]),                  \
      "=v"(T[4]), "=v"(T[5]), "=v"(T[6]), "=v"(T[7])                   \
    : "v"(a), "v"(a2) : "memory")

__global__ __launch_bounds__(256, 1) void mclstm_main(
    const float* __restrict__ xin, const float* __restrict__ Wm,
    const float* __restrict__ Um,  const float* __restrict__ k1,
    const float* __restrict__ bias, const float* __restrict__ bias1,
    float* __restrict__ out, unsigned char* __restrict__ ws)
{
    // gate partials: [parity][wave][row][unit][{i,f,g,o}] -> 16B vector exchange
    __shared__ __align__(16) float predG[2][4][16][16][4];   // 32 KB
    // d partials:   [parity][c][row][wave] -> consumer reads one b128 per c
    __shared__ __align__(16) float predD[2][5][16][4];       // 2.5 KB

    const int tid   = threadIdx.x;
    const int bid   = blockIdx.x;
    const int g_id  = bid & 7;        // batch-row group
    const int w_id  = bid >> 3;       // hidden-unit block [0,32)
    const int lane  = tid & 63;
    const int wv    = tid >> 6;
    const int j0    = w_id * 16;
    const int col16 = lane & 15;
    const int quad  = lane >> 4;

    float* hfin = (float*)(ws + OFF_HFIN);
    float* cfin = (float*)(ws + OFF_CFIN);

    // ---- B-fragments in REGISTERS (constant across all steps) ----
    short8 Bf[5][5];
#pragma unroll
    for (int i = 0; i < 4; ++i) {
        int kb = (wv * 4 + i) * 32 + quad * 8;     // row in U
#pragma unroll
        for (int nt = 0; nt < 5; ++nt) {
            int col = (nt < 4) ? (nt * Hh + j0 + col16)
                               : ((col16 < 5) ? (4 * Hh + col16) : -1);
            short8 b;
#pragma unroll
            for (int j = 0; j < 8; ++j) {
                float v = (col >= 0) ? Um[(size_t)(kb + j) * NGc + col] : 0.f;
                b[j] = (short)f2bf(v);
            }
            Bf[1 + i][nt] = b;
        }
    }
    if (wv < 2) {
        int kb = wv * 32 + quad * 8;               // row in W
#pragma unroll
        for (int nt = 0; nt < 5; ++nt) {
            int col = (nt < 4) ? (nt * Hh + j0 + col16)
                               : ((col16 < 5) ? (4 * Hh + col16) : -1);
            short8 b;
#pragma unroll
            for (int j = 0; j < 8; ++j) {
                float v = (col >= 0) ? Wm[(size_t)(kb + j) * NGc + col] : 0.f;
                b[j] = (short)f2bf(v);
            }
            Bf[0][nt] = b;
        }
    }

    // ---- per-thread cell constants: thread owns (row=tid>>4, unit=tid&15) ----
    const int rrow = tid >> 4, uu = tid & 15;
    const int u_g  = j0 + uu;
    const float bi = bias[0 * Hh + u_g], bf = bias[1 * Hh + u_g];
    const float bg = bias[2 * Hh + u_g], bo = bias[3 * Hh + u_g];
    float bd[5], kv[5];
#pragma unroll
    for (int c = 0; c < 5; ++c) { bd[c] = bias[4 * Hh + c]; kv[c] = k1[c * Hh + u_g]; }
    const float s1v = bias1[u_g], s2v = bias1[Hh + u_g];
    float cpreg = 0.f;

    // publish offset: unit u_g is k-index; tile layout [kb 2048B][quad 512B][row 32B][jj 4B]
    const int kb_p = u_g >> 5, kin = u_g & 31;
    const unsigned pub_off = (unsigned)(kb_p * 2048 + (kin >> 3) * 512 + rrow * 32 + (kin & 7) * 4);

    // ---- spread hint-sample offset (t-invariant): lane samples one tagged
    // ---- dword from producer block 8*wv + (lane>>3), at a spot that hits all
    // ---- 4 waves of each producer (row = 2s covers rrow quads 0..3).
    unsigned hint_off;
    {
        const int hp = lane >> 3, hs = lane & 7;
        const int hu = 16 * (8 * wv + hp) + 2 * hs + 1;   // sampled unit (k-index)
        const int hr = 2 * hs;                            // sampled row
        const int hkb = hu >> 5, hkin = hu & 31;
        hint_off = (unsigned)(hkb * 2048 + (hkin >> 3) * 512 + hr * 32 + (hkin & 7) * 4);
    }

    __syncthreads();

    for (int t = 0; t < Ss; ++t) {
        char* hcur = (char*)ws + OFF_HB + (((t & 1) * 8 + g_id) * 32768);
        char* hnxt = (char*)ws + OFF_HB + ((((t + 1) & 1) * 8 + g_id) * 32768);
        const int pp = t & 1;

        f32x4 acc[5];
#pragma unroll
        for (int nt = 0; nt < 5; ++nt) { f32x4 z = {0.f, 0.f, 0.f, 0.f}; acc[nt] = z; }

        // ---- waves 0,1: own one x k-block; load + MFMA BEFORE poll ----
        if (wv < 2) {
            short8 Ax;
            const float* p = xin + ((size_t)(16 * g_id + col16) * Ss + t) * Ff
                           + wv * 32 + quad * 8;
            f32x4 f0 = *(const f32x4*)(p);
            f32x4 f1 = *(const f32x4*)(p + 4);
#pragma unroll
            for (int j = 0; j < 4; ++j) {
                Ax[j]     = (short)f2bf(f0[j]);
                Ax[4 + j] = (short)f2bf(f1[j]);
            }
#pragma unroll
            for (int nt = 0; nt < 5; ++nt)
                acc[nt] = __builtin_amdgcn_mfma_f32_16x16x32_bf16(Ax, Bf[0][nt], acc[nt], 0, 0, 0);
        }

        // ---- cheap spread-hint spin: 1 tagged dword per lane (256B/wave/iter,
        // ---- 32x less LLC traffic than a full HL8 sweep; spread over the whole
        // ---- tile region so no hot-spot). Samples ARE payload words, so there
        // ---- is no producer-side lag. Advisory only; HL8 verify below is the
        // ---- correctness gate.
        {
            unsigned long long ha = (unsigned long long)(hcur + hint_off);
            const unsigned texp = (unsigned)t;
            for (int it = 0; it < (1 << 22); ++it) {
                unsigned hv;
                asm volatile(
                    "global_load_dword %0, %1, off sc0 sc1\n\t"
                    "s_waitcnt vmcnt(0)"
                    : "=v"(hv) : "v"(ha) : "memory");
                if (__all((int)((hv >> 16) == texp))) break;
            }
        }

        // ---- tagged payload load + verify (expect ~1 iteration after hint) ----
        i32x4a T[8];
        {
            unsigned long long hb = (unsigned long long)
                (hcur + (wv * 4) * 2048 + quad * 512 + col16 * 32);
            unsigned long long hb2 = hb + 4096;
            const unsigned expect = (unsigned)t << 16;
            for (int it = 0; it < (1 << 22); ++it) {
                HL8(T, hb, hb2);
                unsigned diff = 0u;
#pragma unroll
                for (int i = 0; i < 8; ++i)
#pragma unroll
                    for (int j = 0; j < 4; ++j)
                        diff |= ((unsigned)T[i][j]) ^ expect;
                if (__all((int)((diff >> 16) == 0u))) break;
            }
        }

        // ---- repack tagged dwords -> bf16 A-frags, MFMA ----
#pragma unroll
        for (int i = 0; i < 4; ++i) {
            short8 a;
#pragma unroll
            for (int j = 0; j < 4; ++j) {
                a[j]     = (short)(T[2 * i][j] & 0xFFFF);
                a[4 + j] = (short)(T[2 * i + 1][j] & 0xFFFF);
            }
#pragma unroll
            for (int nt = 0; nt < 5; ++nt)
                acc[nt] = __builtin_amdgcn_mfma_f32_16x16x32_bf16(a, Bf[1 + i][nt], acc[nt], 0, 0, 0);
        }

        // ---- write K-split partials: gates as one f32x4 per (row,unit) ----
#pragma unroll
        for (int j = 0; j < 4; ++j) {
            f32x4 g4 = {acc[0][j], acc[1][j], acc[2][j], acc[3][j]};
            *(f32x4*)&predG[pp][wv][quad * 4 + j][col16][0] = g4;
        }
        if (col16 < 5) {
#pragma unroll
            for (int j = 0; j < 4; ++j)
                predD[pp][col16][quad * 4 + j][wv] = acc[4][j];
        }
        __syncthreads();                  // the ONLY barrier per step

        // ---- reduce + cell update + tagged register->LLC publish ----
        {
            f32x4 g4 = {bi, bf, bg, bo};
#pragma unroll
            for (int w = 0; w < 4; ++w) {
                f32x4 p = *(const f32x4*)&predG[pp][w][rrow][uu][0];
                g4 += p;
            }
            float dv[5];
#pragma unroll
            for (int c = 0; c < 5; ++c) {
                f32x4 dp = *(const f32x4*)&predD[pp][c][rrow][0];
                dv[c] = bd[c] + ((dp[0] + dp[1]) + (dp[2] + dp[3]));
            }
            // softmax(tanh(.)): tanh in [-1,1] -> no max-subtraction needed
            float sden = 0.f;
#pragma unroll
            for (int c = 0; c < 5; ++c) { dv[c] = __expf(ftanh(dv[c])); sden += dv[c]; }
            float inv = frcp(sden);
#pragma unroll
            for (int c = 0; c < 5; ++c) dv[c] *= inv;

            float i_ = fsig(g4[0]);
            float f_ = fsig(g4[1]);
            float g_ = ftanh(g4[2]);
            float o_ = fsig(g4[3]);
            float c1v = ftanh(g_);
            float c5v = cpreg;
            float c3v = f_ * c5v + i_ * g_;
            float c2v = s2v * c3v + (1.f - s2v) * c1v;
            float c4v = s1v * c3v + (1.f - s1v) * c5v;
            float cn = dv[0] * kv[0] * c1v + dv[1] * kv[1] * c2v + dv[2] * kv[2] * c3v
                     + dv[3] * kv[3] * c4v + dv[4] * kv[4] * c5v;
            float hn = o_ * ftanh(cn);
            cpreg = cn;

            if (t < Ss - 1) {
                unsigned word = ((unsigned)(t + 1) << 16) | (unsigned)f2bf(hn);
                __hip_atomic_store((unsigned*)(hnxt + pub_off), word,
                                   __ATOMIC_RELAXED, __HIP_MEMORY_SCOPE_AGENT);
            } else {
                size_t off = (size_t)(16 * g_id + rrow) * Hh + u_g;
                hfin[off] = hn;
                cfin[0 * Bb * Hh + off] = c1v;
                cfin[1 * Bb * Hh + off] = c2v;
                cfin[2 * Bb * Hh + off] = c3v;
                cfin[3 * Bb * Hh + off] = c4v;
                cfin[4 * Bb * Hh + off] = c5v;
                if (w_id == 0 && uu == 0) {
#pragma unroll
                    for (int c = 0; c < 5; ++c)
                        out[1408 + (16 * g_id + rrow) * 5 + c] = dv[c];
                }
            }
        }
        // no end-of-step barrier: pred is parity-buffered; the next step's
        // shared barrier orders read(t) before write(t+2).
    }
}

// ---- heads: stage A: r1 = relu(h@rw1+rb1); y1[hd] = relu(c_hd@dw1+db1) ----
__global__ __launch_bounds__(256) void stageA(const unsigned char* __restrict__ ws,
    const float* __restrict__ rw1, const float* __restrict__ rb1,
    const float* __restrict__ dw1, const float* __restrict__ db1)
{
    __shared__ float sW[512 * 17];
    const int tid = threadIdx.x;
    const int blk = blockIdx.x;
    const float* hfin = (const float*)(ws + OFF_HFIN);
    const float* cfin = (const float*)(ws + OFF_CFIN);
    float* r1 = (float*)(ws + OFF_R1);
    float* y1 = (float*)(ws + OFF_Y1);

    const float* src; const float* Wm; const float* bv; float* dst; int cblk;
    if (blk < 16) { src = hfin; Wm = rw1; bv = rb1; dst = r1; cblk = blk; }
    else {
        int hd = (blk - 16) >> 4; cblk = (blk - 16) & 15;
        src = cfin + (size_t)hd * Bb * Hh; Wm = dw1; bv = db1;
        dst = y1 + (size_t)hd * Bb * 256;
    }
    for (int e = tid; e < 512 * 16; e += 256) {
        int k = e >> 4, c = e & 15;
        sW[k * 17 + c] = Wm[(size_t)k * 256 + cblk * 16 + c];
    }
    __syncthreads();
    for (int e = tid; e < 128 * 16; e += 256) {
        int r = e >> 4, c = e & 15;
        float a = bv[cblk * 16 + c];
        const float* sp = src + (size_t)r * 512;
        for (int k = 0; k < 512; k += 4) {
            f32x4 h4 = *(const f32x4*)(sp + k);
            a += h4[0] * sW[(k + 0) * 17 + c] + h4[1] * sW[(k + 1) * 17 + c]
               + h4[2] * sW[(k + 2) * 17 + c] + h4[3] * sW[(k + 3) * 17 + c];
        }
        dst[(size_t)r * 256 + cblk * 16 + c] = fmaxf(a, 0.f);
    }
}

// ---- stage B: r2 = relu(r1@rw2+rb2) ----
__global__ __launch_bounds__(256) void stageB(const unsigned char* __restrict__ ws,
    const float* __restrict__ rw2, const float* __restrict__ rb2)
{
    __shared__ float sW[256 * 17];
    const int tid = threadIdx.x;
    const int cblk = blockIdx.x;
    const float* r1 = (const float*)(ws + OFF_R1);
    float* r2 = (float*)(ws + OFF_R2);
    for (int e = tid; e < 256 * 16; e += 256) {
        int k = e >> 4, c = e & 15;
        sW[k * 17 + c] = rw2[(size_t)k * 128 + cblk * 16 + c];
    }
    __syncthreads();
    for (int e = tid; e < 128 * 16; e += 256) {
        int r = e >> 4, c = e & 15;
        float a = rb2[cblk * 16 + c];
        const float* sp = r1 + (size_t)r * 256;
        for (int k = 0; k < 256; k += 4) {
            f32x4 h4 = *(const f32x4*)(sp + k);
            a += h4[0] * sW[(k + 0) * 17 + c] + h4[1] * sW[(k + 1) * 17 + c]
               + h4[2] * sW[(k + 2) * 17 + c] + h4[3] * sW[(k + 3) * 17 + c];
        }
        r2[(size_t)r * 128 + cblk * 16 + c] = fmaxf(a, 0.f);
    }
}

// ---- stage C: BN + final projections + log_softmax ----
__global__ __launch_bounds__(256) void stageC(const unsigned char* __restrict__ ws,
    const float* __restrict__ rbng, const float* __restrict__ rbnb,
    const float* __restrict__ rw3,  const float* __restrict__ rb3,
    const float* __restrict__ dbng, const float* __restrict__ dbnb,
    const float* __restrict__ dw2,  const float* __restrict__ db2,
    float* __restrict__ out)
{
    __shared__ float sc[256], sh[256];
    const int tid = threadIdx.x;
    const int blk = blockIdx.x;
    const float* r2 = (const float*)(ws + OFF_R2);
    const float* y1 = (const float*)(ws + OFF_Y1);
    if (blk == 0) {
        if (tid < 128) {
            int c = tid; float s = 0.f, s2 = 0.f;
            for (int r = 0; r < 128; ++r) { float x = r2[r * 128 + c]; s += x; s2 += x * x; }
            float m = s * (1.f / 128.f), v = s2 * (1.f / 128.f) - m * m;
            float sca = rbng[c] * rsqrtf(v + 1e-5f);
            sc[c] = sca; sh[c] = rbnb[c] - m * sca;
        }
        __syncthreads();
        if (tid < 128) {
            int r = tid; float a = rb3[0];
            for (int c = 0; c < 128; ++c)
                a += (r2[r * 128 + c] * sc[c] + sh[c]) * rw3[c];
            out[r] = a;
        }
    } else {
        int hd = blk - 1;
        const float* y = y1 + (size_t)hd * 128 * 256;
        {
            int c = tid; float s = 0.f, s2 = 0.f;
            for (int r = 0; r < 128; ++r) { float x = y[r * 256 + c]; s += x; s2 += x * x; }
            float m = s * (1.f / 128.f), v = s2 * (1.f / 128.f) - m * m;
            float sca = dbng[c] * rsqrtf(v + 1e-5f);
            sc[c] = sca; sh[c] = dbnb[c] - m * sca;
        }
        __syncthreads();
        if (tid < 128) {
            int r = tid;
            float z0 = db2[0], z1 = db2[1];
            for (int c = 0; c < 256; ++c) {
                float yn = y[r * 256 + c] * sc[c] + sh[c];
                z0 += yn * dw2[c * 2 + 0];
                z1 += yn * dw2[c * 2 + 1];
            }
            float mx = fmaxf(z0, z1);
            float ls = mx + logf(__expf(z0 - mx) + __expf(z1 - mx));
            out[128 + hd * 256 + r * 2 + 0] = z0 - ls;
            out[128 + hd * 256 + r * 2 + 1] = z1 - ls;
        }
    }
}

extern "C" void kernel_launch(void* const* d_in, const int* in_sizes, int n_in,
                              void* d_out, int out_size, void* d_ws, size_t ws_size,
                              hipStream_t stream) {
    const float* x    = (const float*)d_in[0];
    const float* Wm   = (const float*)d_in[1];
    const float* Um   = (const float*)d_in[2];
    const float* k1   = (const float*)d_in[3];
    const float* bias = (const float*)d_in[4];
    const float* b1   = (const float*)d_in[5];
    const float* rw1  = (const float*)d_in[6];
    const float* rb1  = (const float*)d_in[7];
    const float* rw2  = (const float*)d_in[8];
    const float* rb2  = (const float*)d_in[9];
    const float* rbng = (const float*)d_in[10];
    const float* rbnb = (const float*)d_in[11];
    const float* rw3  = (const float*)d_in[12];
    const float* rb3  = (const float*)d_in[13];
    const float* dw1  = (const float*)d_in[14];
    const float* db1  = (const float*)d_in[15];
    const float* dbng = (const float*)d_in[16];
    const float* dbnb = (const float*)d_in[17];
    const float* dw2  = (const float*)d_in[18];
    const float* db2  = (const float*)d_in[19];
    (void)in_sizes; (void)n_in; (void)out_size; (void)ws_size;

    // zero both tagged h tile parities (tag 0 == step 0, h0 = 0)
    hipMemsetAsync(d_ws, 0, OFF_HFIN, stream);

    mclstm_main<<<256, 256, 0, stream>>>(x, Wm, Um, k1, bias, b1,
                                         (float*)d_out, (unsigned char*)d_ws);
    stageA<<<96, 256, 0, stream>>>((const unsigned char*)d_ws, rw1, rb1, dw1, db1);
    stageB<<<8, 256, 0, stream>>>((const unsigned char*)d_ws, rw2, rb2);
    stageC<<<6, 256, 0, stream>>>((const unsigned char*)d_ws, rbng, rbnb, rw3, rb3,
                                  dbng, dbnb, dw2, db2, (float*)d_out);
}

// Round 4
// 1356.002 us; speedup vs baseline: 2.2229x; 1.0668x over previous
//
#include <hip/hip_runtime.h>
#include <hip/hip_bf16.h>
#include <math.h>

#define Bb   128
#define Ss   512
#define Ff   64
#define Hh   512
#define NGc  2053          // 4*H + 5
#define Kk   576           // F + H

// workspace layout (bytes)
#define OFF_HB    4096                     // 2 parities x 8 groups x 32768 B tagged h tiles (LLC path)
#define OFF_HFIN  528384                   // B*H fp32
#define OFF_CFIN  790528                   // 5 x B*H fp32
#define OFF_R1    2101248                  // 128x256 fp32
#define OFF_R2    2232320                  // 128x128 fp32
#define OFF_Y1    2297856                  // 5 x 128x256 fp32
// XCD-local mirror of the tagged h tiles: 2 parities x 8 groups x 32768 B.
// Lives ONLY during mclstm_main; overlaps the R1/R2/Y1 scratch (written later).
#define OFF_MHB   2101248
#define MHB_BYTES 524288

typedef __attribute__((ext_vector_type(8))) short short8;
typedef __attribute__((ext_vector_type(4))) float f32x4;
typedef __attribute__((ext_vector_type(4))) int   i32x4a;

__device__ __forceinline__ unsigned short f2bf(float f) {
    union { float f; unsigned u; } v; v.f = f;
    unsigned r = v.u + 0x7fffu + ((v.u >> 16) & 1u);
    return (unsigned short)(r >> 16);
}

__device__ __forceinline__ float frcp(float x) { return __builtin_amdgcn_rcpf(x); }

// overflow-safe fast tanh via v_exp + v_rcp (no slow fp32 div sequence)
__device__ __forceinline__ float ftanh(float x) {
    float ax = fabsf(x);
    float t  = __expf(-2.f * ax);
    float r  = (1.f - t) * frcp(1.f + t);
    return copysignf(r, x);
}
__device__ __forceinline__ float fsig(float x) {
    return frcp(1.f + __expf(-x));
}

// 8 coalescing 16B loads covering this wave's 4 tagged h k-blocks.
// LLC-coherent variant (cross-XCD safe): sc0 sc1.
#define HL8(T, a, a2)                                                  \
  asm volatile(                                                        \
    "global_load_dwordx4 %0, %8, off sc0 sc1\n\t"                      \
    "global_load_dwordx4 %1, %8, off offset:16 sc0 sc1\n\t"            \
    "global_load_dwordx4 %2, %8, off offset:2048 sc0 sc1\n\t"          \
    "global_load_dwordx4 %3, %8, off offset:2064 sc0 sc1\n\t"          \
    "global_load_dwordx4 %4, %9, off sc0 sc1\n\t"                      \
    "global_load_dwordx4 %5, %9, off offset:16 sc0 sc1\n\t"            \
    "global_load_dwordx4 %6, %9, off offset:2048 sc0 sc1\n\t"          \
    "global_load_dwordx4 %7, %9, off offset:2064 sc0 sc1\n\t"          \
    "s_waitcnt vmcnt(0)"                                               \
    : "=v"(T[0]), "=v"(T[1]), "=v"(T[2]), "=v"(T[3]),                  \
      "=v"(T[4]), "=v"(T[5]), "=v"(T[6]), "=v"(T[7])                   \
    : "v"(a), "v"(a2) : "memory")

// XCD-local variant: sc0 only (bypass the per-CU L1, read the XCD-shared L2).
#define HL8S(T, a, a2)                                                 \
  asm volatile(                                                        \
    "global_load_dwordx4 %0, %8, off sc0\n\t"                          \
    "global_load_dwordx4 %1, %8, off offset:16 sc0\n\t"                \
    "global_load_dwordx4 %2, %8, off offset:2048 sc0\n\t"              \
    "global_load_dwordx4 %3, %8, off offset:2064 sc0\n\t"              \
    "global_load_dwordx4 %4, %9, off sc0\n\t"                          \
    "global_load_dwordx4 %5, %9, off offset:16 sc0\n\t"                \
    "global_load_dwordx4 %6, %9, off offset:2048 sc0\n\t"              \
    "global_load_dwordx4 %7, %9, off offset:2064 sc0\n\t"              \
    "s_waitcnt vmcnt(0)"                                               \
    : "=v"(T[0]), "=v"(T[1]), "=v"(T[2]), "=v"(T[3]),                  \
      "=v"(T[4]), "=v"(T[5]), "=v"(T[6]), "=v"(T[7])                   \
    : "v"(a), "v"(a2) : "memory")

__global__ __launch_bounds__(256, 1) void mclstm_main(
    const float* __restrict__ xin, const float* __restrict__ Wm,
    const float* __restrict__ Um,  const float* __restrict__ k1,
    const float* __restrict__ bias, const float* __restrict__ bias1,
    float* __restrict__ out, unsigned char* __restrict__ ws)
{
    // gate partials: [parity][wave][row][unit][{i,f,g,o}] -> 16B vector exchange
    __shared__ __align__(16) float predG[2][4][16][16][4];   // 32 KB
    // d partials:   [parity][c][row][wave] -> consumer reads one b128 per c
    __shared__ __align__(16) float predD[2][5][16][4];       // 2.5 KB

    const int tid   = threadIdx.x;
    const int bid   = blockIdx.x;
    const int g_id  = bid & 7;        // batch-row group
    const int w_id  = bid >> 3;       // hidden-unit block [0,32)
    const int lane  = tid & 63;
    const int wv    = tid >> 6;
    const int j0    = w_id * 16;
    const int col16 = lane & 15;
    const int quad  = lane >> 4;

    float* hfin = (float*)(ws + OFF_HFIN);
    float* cfin = (float*)(ws + OFF_CFIN);

    // ---- B-fragments in REGISTERS (constant across all steps) ----
    short8 Bf[5][5];
#pragma unroll
    for (int i = 0; i < 4; ++i) {
        int kb = (wv * 4 + i) * 32 + quad * 8;     // row in U
#pragma unroll
        for (int nt = 0; nt < 5; ++nt) {
            int col = (nt < 4) ? (nt * Hh + j0 + col16)
                               : ((col16 < 5) ? (4 * Hh + col16) : -1);
            short8 b;
#pragma unroll
            for (int j = 0; j < 8; ++j) {
                float v = (col >= 0) ? Um[(size_t)(kb + j) * NGc + col] : 0.f;
                b[j] = (short)f2bf(v);
            }
            Bf[1 + i][nt] = b;
        }
    }
    if (wv < 2) {
        int kb = wv * 32 + quad * 8;               // row in W
#pragma unroll
        for (int nt = 0; nt < 5; ++nt) {
            int col = (nt < 4) ? (nt * Hh + j0 + col16)
                               : ((col16 < 5) ? (4 * Hh + col16) : -1);
            short8 b;
#pragma unroll
            for (int j = 0; j < 8; ++j) {
                float v = (col >= 0) ? Wm[(size_t)(kb + j) * NGc + col] : 0.f;
                b[j] = (short)f2bf(v);
            }
            Bf[0][nt] = b;
        }
    }

    // ---- per-thread cell constants: thread owns (row=tid>>4, unit=tid&15) ----
    const int rrow = tid >> 4, uu = tid & 15;
    const int u_g  = j0 + uu;
    const float bi = bias[0 * Hh + u_g], bf = bias[1 * Hh + u_g];
    const float bg = bias[2 * Hh + u_g], bo = bias[3 * Hh + u_g];
    float bd[5], kv[5];
#pragma unroll
    for (int c = 0; c < 5; ++c) { bd[c] = bias[4 * Hh + c]; kv[c] = k1[c * Hh + u_g]; }
    const float s1v = bias1[u_g], s2v = bias1[Hh + u_g];
    float cpreg = 0.f;

    // publish offset: unit u_g is k-index; tile layout [kb 2048B][quad 512B][row 32B][jj 4B]
    const int kb_p = u_g >> 5, kin = u_g & 31;
    const unsigned pub_off = (unsigned)(kb_p * 2048 + (kin >> 3) * 512 + rrow * 32 + (kin & 7) * 4);

    // fast path = XCD-local mirror exchange. Probed EMPIRICALLY (bounded spin,
    // latch to slow on failure). No topology/hwreg assumption; producers always
    // dual-publish, so the slow LLC path below is always live -> no deadlock.
    bool use_fast = true;

    __syncthreads();

    for (int t = 0; t < Ss; ++t) {
        char* hcur = (char*)ws + OFF_HB  + (((t & 1) * 8 + g_id) * 32768);
        char* hnxt = (char*)ws + OFF_HB  + ((((t + 1) & 1) * 8 + g_id) * 32768);
        char* mcur = (char*)ws + OFF_MHB + (((t & 1) * 8 + g_id) * 32768);
        char* mnxt = (char*)ws + OFF_MHB + ((((t + 1) & 1) * 8 + g_id) * 32768);
        const int pp = t & 1;

        f32x4 acc[5];
#pragma unroll
        for (int nt = 0; nt < 5; ++nt) { f32x4 z = {0.f, 0.f, 0.f, 0.f}; acc[nt] = z; }

        // ---- waves 0,1: own one x k-block; load + MFMA BEFORE poll ----
        if (wv < 2) {
            short8 Ax;
            const float* p = xin + ((size_t)(16 * g_id + col16) * Ss + t) * Ff
                           + wv * 32 + quad * 8;
            f32x4 f0 = *(const f32x4*)(p);
            f32x4 f1 = *(const f32x4*)(p + 4);
#pragma unroll
            for (int j = 0; j < 4; ++j) {
                Ax[j]     = (short)f2bf(f0[j]);
                Ax[4 + j] = (short)f2bf(f1[j]);
            }
#pragma unroll
            for (int nt = 0; nt < 5; ++nt)
                acc[nt] = __builtin_amdgcn_mfma_f32_16x16x32_bf16(Ax, Bf[0][nt], acc[nt], 0, 0, 0);
        }

        // ---- tagged poll+load fused. Fast: bounded spin on the XCD-local
        // ---- mirror through the shared L2 (sc0). On timeout, latch slow and
        // ---- fall through to the unbounded LLC-coherent loop (round-0 path),
        // ---- which producers always feed. Tags are authoritative either way.
        i32x4a T[8];
        {
            const unsigned expect = (unsigned)t << 16;
            bool got = false;
            if (use_fast) {
                unsigned long long mb = (unsigned long long)
                    (mcur + (wv * 4) * 2048 + quad * 512 + col16 * 32);
                unsigned long long mb2 = mb + 4096;
                const int bound = (t == 1) ? 1024 : 256;
                for (int it = 0; it < bound; ++it) {
                    HL8S(T, mb, mb2);
                    unsigned diff = 0u;
#pragma unroll
                    for (int i = 0; i < 8; ++i)
#pragma unroll
                        for (int j = 0; j < 4; ++j)
                            diff |= ((unsigned)T[i][j]) ^ expect;
                    if (__all((int)((diff >> 16) == 0u))) { got = true; break; }
                }
                if (!got) use_fast = false;     // latch; never probe again
            }
            if (!got) {
                unsigned long long hb = (unsigned long long)
                    (hcur + (wv * 4) * 2048 + quad * 512 + col16 * 32);
                unsigned long long hb2 = hb + 4096;
                for (int it = 0; it < (1 << 22); ++it) {
                    HL8(T, hb, hb2);
                    unsigned diff = 0u;
#pragma unroll
                    for (int i = 0; i < 8; ++i)
#pragma unroll
                        for (int j = 0; j < 4; ++j)
                            diff |= ((unsigned)T[i][j]) ^ expect;
                    if (__all((int)((diff >> 16) == 0u))) break;
                }
            }
        }

        // ---- repack tagged dwords -> bf16 A-frags, MFMA ----
#pragma unroll
        for (int i = 0; i < 4; ++i) {
            short8 a;
#pragma unroll
            for (int j = 0; j < 4; ++j) {
                a[j]     = (short)(T[2 * i][j] & 0xFFFF);
                a[4 + j] = (short)(T[2 * i + 1][j] & 0xFFFF);
            }
#pragma unroll
            for (int nt = 0; nt < 5; ++nt)
                acc[nt] = __builtin_amdgcn_mfma_f32_16x16x32_bf16(a, Bf[1 + i][nt], acc[nt], 0, 0, 0);
        }

        // ---- write K-split partials: gates as one f32x4 per (row,unit) ----
#pragma unroll
        for (int j = 0; j < 4; ++j) {
            f32x4 g4 = {acc[0][j], acc[1][j], acc[2][j], acc[3][j]};
            *(f32x4*)&predG[pp][wv][quad * 4 + j][col16][0] = g4;
        }
        if (col16 < 5) {
#pragma unroll
            for (int j = 0; j < 4; ++j)
                predD[pp][col16][quad * 4 + j][wv] = acc[4][j];
        }
        __syncthreads();                  // the ONLY barrier per step

        // ---- reduce + cell update + dual tagged publish ----
        {
            f32x4 g4 = {bi, bf, bg, bo};
#pragma unroll
            for (int w = 0; w < 4; ++w) {
                f32x4 p = *(const f32x4*)&predG[pp][w][rrow][uu][0];
                g4 += p;
            }
            float dv[5];
#pragma unroll
            for (int c = 0; c < 5; ++c) {
                f32x4 dp = *(const f32x4*)&predD[pp][c][rrow][0];
                dv[c] = bd[c] + ((dp[0] + dp[1]) + (dp[2] + dp[3]));
            }
            // softmax(tanh(.)): tanh in [-1,1] -> no max-subtraction needed
            float sden = 0.f;
#pragma unroll
            for (int c = 0; c < 5; ++c) { dv[c] = __expf(ftanh(dv[c])); sden += dv[c]; }
            float inv = frcp(sden);
#pragma unroll
            for (int c = 0; c < 5; ++c) dv[c] *= inv;

            float i_ = fsig(g4[0]);
            float f_ = fsig(g4[1]);
            float g_ = ftanh(g4[2]);
            float o_ = fsig(g4[3]);
            float c1v = ftanh(g_);
            float c5v = cpreg;
            float c3v = f_ * c5v + i_ * g_;
            float c2v = s2v * c3v + (1.f - s2v) * c1v;
            float c4v = s1v * c3v + (1.f - s1v) * c5v;
            float cn = dv[0] * kv[0] * c1v + dv[1] * kv[1] * c2v + dv[2] * kv[2] * c3v
                     + dv[3] * kv[3] * c4v + dv[4] * kv[4] * c5v;
            float hn = o_ * ftanh(cn);
            cpreg = cn;

            if (t < Ss - 1) {
                unsigned word = ((unsigned)(t + 1) << 16) | (unsigned)f2bf(hn);
                // XCD-local mirror publish: plain store, write-through L1 into
                // this XCD's L2. Fire-and-forget; advisory copy.
                *(volatile unsigned*)(mnxt + pub_off) = word;
                // LLC authoritative publish (agent scope, cross-XCD safe).
                __hip_atomic_store((unsigned*)(hnxt + pub_off), word,
                                   __ATOMIC_RELAXED, __HIP_MEMORY_SCOPE_AGENT);
            } else {
                size_t off = (size_t)(16 * g_id + rrow) * Hh + u_g;
                hfin[off] = hn;
                cfin[0 * Bb * Hh + off] = c1v;
                cfin[1 * Bb * Hh + off] = c2v;
                cfin[2 * Bb * Hh + off] = c3v;
                cfin[3 * Bb * Hh + off] = c4v;
                cfin[4 * Bb * Hh + off] = c5v;
                if (w_id == 0 && uu == 0) {
#pragma unroll
                    for (int c = 0; c < 5; ++c)
                        out[1408 + (16 * g_id + rrow) * 5 + c] = dv[c];
                }
            }
        }
        // no end-of-step barrier: pred is parity-buffered; the next step's
        // shared barrier orders read(t) before write(t+2).
    }
}

// ---- heads: stage A: r1 = relu(h@rw1+rb1); y1[hd] = relu(c_hd@dw1+db1) ----
__global__ __launch_bounds__(256) void stageA(const unsigned char* __restrict__ ws,
    const float* __restrict__ rw1, const float* __restrict__ rb1,
    const float* __restrict__ dw1, const float* __restrict__ db1)
{
    __shared__ float sW[512 * 17];
    const int tid = threadIdx.x;
    const int blk = blockIdx.x;
    const float* hfin = (const float*)(ws + OFF_HFIN);
    const float* cfin = (const float*)(ws + OFF_CFIN);
    float* r1 = (float*)(ws + OFF_R1);
    float* y1 = (float*)(ws + OFF_Y1);

    const float* src; const float* Wm; const float* bv; float* dst; int cblk;
    if (blk < 16) { src = hfin; Wm = rw1; bv = rb1; dst = r1; cblk = blk; }
    else {
        int hd = (blk - 16) >> 4; cblk = (blk - 16) & 15;
        src = cfin + (size_t)hd * Bb * Hh; Wm = dw1; bv = db1;
        dst = y1 + (size_t)hd * Bb * 256;
    }
    for (int e = tid; e < 512 * 16; e += 256) {
        int k = e >> 4, c = e & 15;
        sW[k * 17 + c] = Wm[(size_t)k * 256 + cblk * 16 + c];
    }
    __syncthreads();
    for (int e = tid; e < 128 * 16; e += 256) {
        int r = e >> 4, c = e & 15;
        float a = bv[cblk * 16 + c];
        const float* sp = src + (size_t)r * 512;
        for (int k = 0; k < 512; k += 4) {
            f32x4 h4 = *(const f32x4*)(sp + k);
            a += h4[0] * sW[(k + 0) * 17 + c] + h4[1] * sW[(k + 1) * 17 + c]
               + h4[2] * sW[(k + 2) * 17 + c] + h4[3] * sW[(k + 3) * 17 + c];
        }
        dst[(size_t)r * 256 + cblk * 16 + c] = fmaxf(a, 0.f);
    }
}

// ---- stage B: r2 = relu(r1@rw2+rb2) ----
__global__ __launch_bounds__(256) void stageB(const unsigned char* __restrict__ ws,
    const float* __restrict__ rw2, const float* __restrict__ rb2)
{
    __shared__ float sW[256 * 17];
    const int tid = threadIdx.x;
    const int cblk = blockIdx.x;
    const float* r1 = (const float*)(ws + OFF_R1);
    float* r2 = (float*)(ws + OFF_R2);
    for (int e = tid; e < 256 * 16; e += 256) {
        int k = e >> 4, c = e & 15;
        sW[k * 17 + c] = rw2[(size_t)k * 128 + cblk * 16 + c];
    }
    __syncthreads();
    for (int e = tid; e < 128 * 16; e += 256) {
        int r = e >> 4, c = e & 15;
        float a = rb2[cblk * 16 + c];
        const float* sp = r1 + (size_t)r * 256;
        for (int k = 0; k < 256; k += 4) {
            f32x4 h4 = *(const f32x4*)(sp + k);
            a += h4[0] * sW[(k + 0) * 17 + c] + h4[1] * sW[(k + 1) * 17 + c]
               + h4[2] * sW[(k + 2) * 17 + c] + h4[3] * sW[(k + 3) * 17 + c];
        }
        r2[(size_t)r * 128 + cblk * 16 + c] = fmaxf(a, 0.f);
    }
}

// ---- stage C: BN + final projections + log_softmax ----
__global__ __launch_bounds__(256) void stageC(const unsigned char* __restrict__ ws,
    const float* __restrict__ rbng, const float* __restrict__ rbnb,
    const float* __restrict__ rw3,  const float* __restrict__ rb3,
    const float* __restrict__ dbng, const float* __restrict__ dbnb,
    const float* __restrict__ dw2,  const float* __restrict__ db2,
    float* __restrict__ out)
{
    __shared__ float sc[256], sh[256];
    const int tid = threadIdx.x;
    const int blk = blockIdx.x;
    const float* r2 = (const float*)(ws + OFF_R2);
    const float* y1 = (const float*)(ws + OFF_Y1);
    if (blk == 0) {
        if (tid < 128) {
            int c = tid; float s = 0.f, s2 = 0.f;
            for (int r = 0; r < 128; ++r) { float x = r2[r * 128 + c]; s += x; s2 += x * x; }
            float m = s * (1.f / 128.f), v = s2 * (1.f / 128.f) - m * m;
            float sca = rbng[c] * rsqrtf(v + 1e-5f);
            sc[c] = sca; sh[c] = rbnb[c] - m * sca;
        }
        __syncthreads();
        if (tid < 128) {
            int r = tid; float a = rb3[0];
            for (int c = 0; c < 128; ++c)
                a += (r2[r * 128 + c] * sc[c] + sh[c]) * rw3[c];
            out[r] = a;
        }
    } else {
        int hd = blk - 1;
        const float* y = y1 + (size_t)hd * 128 * 256;
        {
            int c = tid; float s = 0.f, s2 = 0.f;
            for (int r = 0; r < 128; ++r) { float x = y[r * 256 + c]; s += x; s2 += x * x; }
            float m = s * (1.f / 128.f), v = s2 * (1.f / 128.f) - m * m;
            float sca = dbng[c] * rsqrtf(v + 1e-5f);
            sc[c] = sca; sh[c] = dbnb[c] - m * sca;
        }
        __syncthreads();
        if (tid < 128) {
            int r = tid;
            float z0 = db2[0], z1 = db2[1];
            for (int c = 0; c < 256; ++c) {
                float yn = y[r * 256 + c] * sc[c] + sh[c];
                z0 += yn * dw2[c * 2 + 0];
                z1 += yn * dw2[c * 2 + 1];
            }
            float mx = fmaxf(z0, z1);
            float ls = mx + logf(__expf(z0 - mx) + __expf(z1 - mx));
            out[128 + hd * 256 + r * 2 + 0] = z0 - ls;
            out[128 + hd * 256 + r * 2 + 1] = z1 - ls;
        }
    }
}

extern "C" void kernel_launch(void* const* d_in, const int* in_sizes, int n_in,
                              void* d_out, int out_size, void* d_ws, size_t ws_size,
                              hipStream_t stream) {
    const float* x    = (const float*)d_in[0];
    const float* Wm   = (const float*)d_in[1];
    const float* Um   = (const float*)d_in[2];
    const float* k1   = (const float*)d_in[3];
    const float* bias = (const float*)d_in[4];
    const float* b1   = (const float*)d_in[5];
    const float* rw1  = (const float*)d_in[6];
    const float* rb1  = (const float*)d_in[7];
    const float* rw2  = (const float*)d_in[8];
    const float* rb2  = (const float*)d_in[9];
    const float* rbng = (const float*)d_in[10];
    const float* rbnb = (const float*)d_in[11];
    const float* rw3  = (const float*)d_in[12];
    const float* rb3  = (const float*)d_in[13];
    const float* dw1  = (const float*)d_in[14];
    const float* db1  = (const float*)d_in[15];
    const float* dbng = (const float*)d_in[16];
    const float* dbnb = (const float*)d_in[17];
    const float* dw2  = (const float*)d_in[18];
    const float* db2  = (const float*)d_in[19];
    (void)in_sizes; (void)n_in; (void)out_size; (void)ws_size;

    // zero both tagged h tile parities (tag 0 == step 0, h0 = 0)
    hipMemsetAsync(d_ws, 0, OFF_HFIN, stream);
    // zero the XCD-local mirror tiles (both parities)
    hipMemsetAsync((char*)d_ws + OFF_MHB, 0, MHB_BYTES, stream);

    mclstm_main<<<256, 256, 0, stream>>>(x, Wm, Um, k1, bias, b1,
                                         (float*)d_out, (unsigned char*)d_ws);
    stageA<<<96, 256, 0, stream>>>((const unsigned char*)d_ws, rw1, rb1, dw1, db1);
    stageB<<<8, 256, 0, stream>>>((const unsigned char*)d_ws, rw2, rb2);
    stageC<<<6, 256, 0, stream>>>((const unsigned char*)d_ws, rbng, rbnb, rw3, rb3,
                                  dbng, dbnb, dw2, db2, (float*)d_out);
}